// Round 13
// baseline (99.605 us; speedup 1.0000x reference)
//
#include <hip/hip_runtime.h>

typedef __attribute__((ext_vector_type(8))) short bf16x8;
typedef __attribute__((ext_vector_type(4))) float f32x4;
typedef __attribute__((ext_vector_type(16))) float f32x16;

#define D_MODEL 1024
#define SEQ 1024
#define NB 4
#define NH 16
#define DH 64
#define MROWS 4096

__device__ __forceinline__ unsigned short f2bf(float f) {
    union { float f; unsigned u; } x; x.f = f;
    unsigned r = x.u + 0x7fffu + ((x.u >> 16) & 1u);
    return (unsigned short)(r >> 16);
}

__device__ __forceinline__ float bf2f(unsigned short u) {
    union { unsigned u; float f; } x; x.u = (unsigned)u << 16;
    return x.f;
}

__device__ __forceinline__ void gload16(const void* g, void* l) {
    __builtin_amdgcn_global_load_lds((const __attribute__((address_space(1))) void*)g,
                                     (__attribute__((address_space(3))) void*)l, 16, 0, 0);
}

// exchange value with lane^32 via permlane32_swap (VALU-only, no LDS)
__device__ __forceinline__ float xhalf(float x, int hi) {
    float a = x, b = x;
    asm volatile("v_permlane32_swap_b32 %0, %1" : "+v"(a), "+v"(b));
    return hi ? b : a;
}

// ---------------- fused preprocessing: cvt_x | transpose_w | pack_mask ----------------
__global__ __launch_bounds__(256) void prep(const float* __restrict__ x,
                                            unsigned short* __restrict__ Xb,
                                            const int* __restrict__ amask,
                                            unsigned long long* __restrict__ mwords,
                                            const float* __restrict__ Wq,
                                            const float* __restrict__ Wk,
                                            const float* __restrict__ Wv,
                                            const float* __restrict__ Wo,
                                            unsigned short* __restrict__ Wqkv_t,
                                            unsigned short* __restrict__ Wo_t) {
    __shared__ float tile[32][33];
    const int bid = blockIdx.x, tid = threadIdx.x;
    if (bid < 4096) {
        int i = bid * 256 + tid;
        float4 v = ((const float4*)x)[i];
        ushort4 r;
        r.x = f2bf(v.x); r.y = f2bf(v.y); r.z = f2bf(v.z); r.w = f2bf(v.w);
        ((ushort4*)Xb)[i] = r;
    } else if (bid < 8192) {
        int t = bid - 4096;
        const int mtx = t >> 10, t10 = t & 1023;
        const float* src = mtx == 0 ? Wq : mtx == 1 ? Wk : mtx == 2 ? Wv : Wo;
        unsigned short* dst = mtx < 3 ? (Wqkv_t + (size_t)mtx * D_MODEL * D_MODEL) : Wo_t;
        const int n0 = (t10 & 31) * 32, k0 = (t10 >> 5) * 32;
        const int tx = tid & 31, ty = tid >> 5;   // 32 x 8
        #pragma unroll
        for (int i = 0; i < 32; i += 8)
            tile[ty + i][tx] = src[(size_t)(k0 + ty + i) * D_MODEL + n0 + tx];
        __syncthreads();
        #pragma unroll
        for (int i = 0; i < 32; i += 8)
            dst[(size_t)(n0 + ty + i) * D_MODEL + k0 + tx] = f2bf(tile[tx][ty + i]);
    } else {
        int word = (bid - 8192) * 4 + (tid >> 6);
        int lane = tid & 63;
        unsigned long long m = __ballot(amask[word * 64 + lane] != 0);
        if (lane == 0) mwords[word] = m;
    }
}

// Cs swizzled addressing: stride 128 shorts, XOR bits 3..5 of col with row&7
#define CSW(r, c) ((r) * 128 + ((c) ^ (((r) & 7) << 3)))

// ---------------- QKV GEMM: BK=64, double-buffered, unrolled x2 (buf compile-time) ----------------
__global__ __launch_bounds__(256) void gemm_qkv(const unsigned short* __restrict__ Xb,
                                                const unsigned short* __restrict__ Wt,
                                                const float* __restrict__ bq,
                                                const float* __restrict__ bk,
                                                const float* __restrict__ bv,
                                                unsigned short* __restrict__ Qb,
                                                unsigned short* __restrict__ Kb,
                                                unsigned short* __restrict__ Vt) {
    __shared__ unsigned short SM[32768];   // 64 KB: [buf][A 8192 | B 8192]; Cs aliases first 32 KB
    const int tid = threadIdx.x;
    const int lane = tid & 63, wid = tid >> 6;
    const int fr = lane & 15, fg = lane >> 4;
    const int wr = wid >> 1, wc = wid & 1;
    const int lin = blockIdx.x;
    const int x = lin & 7, i = lin >> 3;
    const int bxm = (x & 3) * 8 + (i & 7);
    const int byn = (x >> 2) * 12 + (i >> 3);
    const int m0 = bxm * 128, n0 = byn * 128;
    const unsigned short* Ag = Xb + (size_t)m0 * D_MODEL;
    const unsigned short* Bg = Wt + (size_t)n0 * D_MODEL;
    const int srow = tid >> 3;
    const int scol = 8 * ((tid & 7) ^ ((tid >> 3) & 7));
    f32x4 acc[4][4] = {};

#define QSTAGE(bf, kt2)                                                                   \
    {                                                                                     \
        const int kb = (kt2) * 64;                                                        \
        _Pragma("unroll")                                                                 \
        for (int j = 0; j < 4; ++j) {                                                     \
            int row = j * 32 + srow;                                                      \
            gload16(Ag + (size_t)row * D_MODEL + kb + scol, &SM[(bf) * 16384 + (j * 256 + tid) * 8]); \
            gload16(Bg + (size_t)row * D_MODEL + kb + scol, &SM[(bf) * 16384 + 8192 + (j * 256 + tid) * 8]); \
        }                                                                                 \
    }

#define QSTEP(BUF, KT, DOPF)                                                              \
    {                                                                                     \
        if (DOPF) QSTAGE((BUF) ^ 1, (KT) + 1);                                            \
        const unsigned short* As = &SM[(BUF) * 16384];                                    \
        const unsigned short* Bs = &SM[(BUF) * 16384 + 8192];                             \
        _Pragma("unroll")                                                                 \
        for (int ks = 0; ks < 2; ++ks) {                                                  \
            bf16x8 af[4], bfv[4];                                                         \
            _Pragma("unroll")                                                             \
            for (int m = 0; m < 4; ++m) {                                                 \
                int row = wr * 64 + m * 16 + fr;                                          \
                af[m] = *(const bf16x8*)&As[row * 64 + ((ks * 32 + fg * 8) ^ ((row & 7) * 8))]; \
            }                                                                             \
            _Pragma("unroll")                                                             \
            for (int n = 0; n < 4; ++n) {                                                 \
                int row = wc * 64 + n * 16 + fr;                                          \
                bfv[n] = *(const bf16x8*)&Bs[row * 64 + ((ks * 32 + fg * 8) ^ ((row & 7) * 8))]; \
            }                                                                             \
            __builtin_amdgcn_s_setprio(1);                                                \
            _Pragma("unroll")                                                             \
            for (int m = 0; m < 4; ++m)                                                   \
                _Pragma("unroll")                                                         \
                for (int n = 0; n < 4; ++n)                                               \
                    acc[m][n] = __builtin_amdgcn_mfma_f32_16x16x32_bf16(af[m], bfv[n], acc[m][n], 0, 0, 0); \
            __builtin_amdgcn_s_setprio(0);                                                \
        }                                                                                 \
        __syncthreads();                                                                  \
    }

    QSTAGE(0, 0);
    __syncthreads();
    for (int kt2 = 0; kt2 < 8; ++kt2) {
        QSTEP(0, 2 * kt2, 1);
        QSTEP(1, 2 * kt2 + 1, (kt2 < 7));
    }
#undef QSTEP
#undef QSTAGE
    unsigned short* Cs = SM;
    const int sel = n0 >> 10;
    const int npb = n0 & 1023;
    if (sel < 2) {
        #pragma unroll
        for (int n = 0; n < 4; ++n) {
            int cn = wc * 64 + n * 16 + fr;
            float bias = (sel == 0 ? bq : bk)[npb + cn];
            #pragma unroll
            for (int m = 0; m < 4; ++m)
                #pragma unroll
                for (int r = 0; r < 4; ++r) {
                    int row = wr * 64 + m * 16 + fg * 4 + r;
                    Cs[CSW(row, cn)] = f2bf(acc[m][n][r] + bias);
                }
        }
        __syncthreads();
        unsigned short* dst = sel == 0 ? Qb : Kb;
        #pragma unroll
        for (int k = 0; k < 8; ++k) {
            int c = k * 256 + tid;
            int row = c >> 4, cc = c & 15;
            int np = npb + cc * 8;
            int h = np >> 6, d = np & 63;
            int gm = m0 + row, b = gm >> 10, s = gm & 1023;
            bf16x8 v = *(const bf16x8*)&Cs[CSW(row, cc * 8)];
            *(bf16x8*)&dst[((size_t)(b * NH + h) * SEQ + s) * DH + d] = v;
        }
    } else {
        #pragma unroll
        for (int n = 0; n < 4; ++n) {
            int cn = wc * 64 + n * 16 + fr;
            float bias = bv[npb + cn];
            #pragma unroll
            for (int m = 0; m < 4; ++m)
                #pragma unroll
                for (int r = 0; r < 4; ++r) {
                    int row = wr * 64 + m * 16 + fg * 4 + r;   // s index
                    Cs[CSW(cn, row)] = f2bf(acc[m][n][r] + bias);
                }
        }
        __syncthreads();
        #pragma unroll
        for (int k = 0; k < 8; ++k) {
            int c = k * 256 + tid;
            int dcol = c >> 4, scc = c & 15;
            int np = npb + dcol;
            int h = np >> 6, dd = np & 63;
            int gm0 = m0 + scc * 8, b = gm0 >> 10, s0 = gm0 & 1023;
            bf16x8 v = *(const bf16x8*)&Cs[CSW(dcol, scc * 8)];
            *(bf16x8*)&Vt[((size_t)(b * NH + h) * DH + dd) * SEQ + s0] = v;
        }
    }
}

// ---------------- O-proj GEMM: BK=64, double-buffered, unrolled x2, bf16 output ----------------
__global__ __launch_bounds__(256) void gemm_o(const unsigned short* __restrict__ Ab,
                                              const unsigned short* __restrict__ Wt,
                                              unsigned short* __restrict__ tmpb) {
    __shared__ unsigned short SM[32768];   // 64 KB dbuf; Cs aliases first 32 KB
    const int tid = threadIdx.x;
    const int lane = tid & 63, wid = tid >> 6;
    const int fr = lane & 15, fg = lane >> 4;
    const int wr = wid >> 1, wc = wid & 1;
    const int lin = blockIdx.x;
    const int x = lin & 7, i = lin >> 3;
    const int bxm = (x & 3) * 8 + (i & 7);
    const int byn = (x >> 2) * 4 + (i >> 3);
    const int m0 = bxm * 128, n0 = byn * 128;
    const unsigned short* Ag = Ab + (size_t)m0 * D_MODEL;
    const unsigned short* Bg = Wt + (size_t)n0 * D_MODEL;
    const int srow = tid >> 3;
    const int scol = 8 * ((tid & 7) ^ ((tid >> 3) & 7));
    f32x4 acc[4][4] = {};

#define OSTAGE(bf, kt2)                                                                   \
    {                                                                                     \
        const int kb = (kt2) * 64;                                                        \
        _Pragma("unroll")                                                                 \
        for (int j = 0; j < 4; ++j) {                                                     \
            int row = j * 32 + srow;                                                      \
            gload16(Ag + (size_t)row * D_MODEL + kb + scol, &SM[(bf) * 16384 + (j * 256 + tid) * 8]); \
            gload16(Bg + (size_t)row * D_MODEL + kb + scol, &SM[(bf) * 16384 + 8192 + (j * 256 + tid) * 8]); \
        }                                                                                 \
    }

#define OSTEP(BUF, KT, DOPF)                                                              \
    {                                                                                     \
        if (DOPF) OSTAGE((BUF) ^ 1, (KT) + 1);                                            \
        const unsigned short* As = &SM[(BUF) * 16384];                                    \
        const unsigned short* Bs = &SM[(BUF) * 16384 + 8192];                             \
        _Pragma("unroll")                                                                 \
        for (int ks = 0; ks < 2; ++ks) {                                                  \
            bf16x8 af[4], bfv[4];                                                         \
            _Pragma("unroll")                                                             \
            for (int m = 0; m < 4; ++m) {                                                 \
                int row = wr * 64 + m * 16 + fr;                                          \
                af[m] = *(const bf16x8*)&As[row * 64 + ((ks * 32 + fg * 8) ^ ((row & 7) * 8))]; \
            }                                                                             \
            _Pragma("unroll")                                                             \
            for (int n = 0; n < 4; ++n) {                                                 \
                int row = wc * 64 + n * 16 + fr;                                          \
                bfv[n] = *(const bf16x8*)&Bs[row * 64 + ((ks * 32 + fg * 8) ^ ((row & 7) * 8))]; \
            }                                                                             \
            __builtin_amdgcn_s_setprio(1);                                                \
            _Pragma("unroll")                                                             \
            for (int m = 0; m < 4; ++m)                                                   \
                _Pragma("unroll")                                                         \
                for (int n = 0; n < 4; ++n)                                               \
                    acc[m][n] = __builtin_amdgcn_mfma_f32_16x16x32_bf16(af[m], bfv[n], acc[m][n], 0, 0, 0); \
            __builtin_amdgcn_s_setprio(0);                                                \
        }                                                                                 \
        __syncthreads();                                                                  \
    }

    OSTAGE(0, 0);
    __syncthreads();
    for (int kt2 = 0; kt2 < 8; ++kt2) {
        OSTEP(0, 2 * kt2, 1);
        OSTEP(1, 2 * kt2 + 1, (kt2 < 7));
    }
#undef OSTEP
#undef OSTAGE
    unsigned short* Cs = SM;
    #pragma unroll
    for (int n = 0; n < 4; ++n) {
        int cn = wc * 64 + n * 16 + fr;
        #pragma unroll
        for (int m = 0; m < 4; ++m)
            #pragma unroll
            for (int r = 0; r < 4; ++r) {
                int row = wr * 64 + m * 16 + fg * 4 + r;
                Cs[CSW(row, cn)] = f2bf(acc[m][n][r]);
            }
    }
    __syncthreads();
    #pragma unroll
    for (int k = 0; k < 8; ++k) {
        int c = k * 256 + tid;
        int row = c >> 4, cc = c & 15;
        bf16x8 v = *(const bf16x8*)&Cs[CSW(row, cc * 8)];
        *(bf16x8*)&tmpb[(size_t)(m0 + row) * D_MODEL + n0 + cc * 8] = v;
    }
}

// ---------------- flash attention: 8-wave blocks (QBLK=256), KVBLK=128, in-register softmax ----------------
// Grid 256 = 1 block/CU. K/V staging and barriers amortize over 8 waves; per-thread stage
// instructions halve (2+2 gload16). Mask via K-side bias MFMA; row-sum via mfma(ones, P).
__global__ __launch_bounds__(512, 2) void attn_kernel(const unsigned short* __restrict__ Qb,
                                                      const unsigned short* __restrict__ Kb,
                                                      const unsigned short* __restrict__ Vt,
                                                      const unsigned long long* __restrict__ mwords,
                                                      unsigned short* __restrict__ AF) {
    __shared__ unsigned short Ks[2][128 * 64];   // [kv][d]
    __shared__ unsigned short Vts[2][64 * 128];  // [d][kv]
    const int tid = threadIdx.x, lane = tid & 63, wid = tid >> 6;   // wid 0..7
    const int l31 = lane & 31, hi = lane >> 5;
    const int lin = blockIdx.x;                  // 256 blocks
    const int x = lin & 7, i = lin >> 3;         // i in 0..31
    const int bh = x * 8 + (i >> 2);             // 8 heads per XCD
    const int qt = i & 3;
    const int b = bh >> 4;
    const unsigned short* Qh = Qb + (size_t)bh * SEQ * DH;
    const unsigned short* Kh = Kb + (size_t)bh * SEQ * DH;
    const unsigned short* Vth = Vt + (size_t)bh * DH * SEQ;
    const unsigned long long* mwb = mwords + b * 16;
    const int q0 = qt * 256 + wid * 32;

    bf16x8 qf[4];
    #pragma unroll
    for (int ks = 0; ks < 4; ++ks)
        qf[ks] = *(const bf16x8*)(Qh + (size_t)(q0 + l31) * DH + ks * 16 + hi * 8);

    union U4 { unsigned u[4]; bf16x8 v; };
    U4 ones;
    ones.u[0] = 0x3F803F80u; ones.u[1] = 0x3F803F80u;
    ones.u[2] = 0x3F803F80u; ones.u[3] = 0x3F803F80u;

    f32x16 oacc0 = {}, oacc1 = {};
    f32x16 sacc = {};                // running P row-sum (all 16 regs identical)
    float mrun = -3.0e38f;
    const float C2 = 0.18033688f;    // 0.125 * log2(e)

#define KSWZ(row, colsh) ((row) * 64 + ((colsh) ^ (((row) & 7) << 3)))
#define VSWZ(row, colsh) ((row) * 128 + ((colsh) ^ (((row) & 7) << 3)))
// 512 threads: K tile (128x64, 16KB) = 2 chunks/thread; V tile (64x128) = 2 chunks/thread.
#define STAGE(bufi, kt2)                                                                  \
    {                                                                                     \
        const int kv0s = (kt2) * 128;                                                     \
        _Pragma("unroll")                                                                 \
        for (int j = 0; j < 2; ++j) {                                                     \
            const int c = j * 512 + tid;                                                  \
            const int krow = c >> 3;                                                      \
            const int kcol = 8 * ((c & 7) ^ (krow & 7));                                  \
            gload16(Kh + (size_t)(kv0s + krow) * DH + kcol, &Ks[bufi][c * 8]);            \
            const int vrow = c >> 4;                                                      \
            const int vcol = 8 * ((c & 15) ^ (vrow & 7));                                 \
            gload16(Vth + (size_t)vrow * SEQ + kv0s + vcol, &Vts[bufi][c * 8]);           \
        }                                                                                 \
    }

#define ATILE(BUF, KT, DOPF)                                                              \
    {                                                                                     \
        if (DOPF) STAGE((BUF) ^ 1, (KT) + 1);                                             \
        const unsigned long long mwA = mwb[2 * (KT)], mwB = mwb[2 * (KT) + 1];            \
        const unsigned mr0 = (unsigned)mwA, mr1 = (unsigned)(mwA >> 32);                  \
        const unsigned mr2 = (unsigned)mwB, mr3 = (unsigned)(mwB >> 32);                  \
        f32x16 sA0 = {}, sA1 = {}, sB0 = {}, sB1 = {};                                    \
        __builtin_amdgcn_s_setprio(1);                                                    \
        _Pragma("unroll")                                                                 \
        for (int ks = 0; ks < 4; ++ks) {                                                  \
            const int ch = ks * 16 + hi * 8;                                              \
            bf16x8 k0 = *(const bf16x8*)&Ks[BUF][KSWZ(l31, ch)];                          \
            bf16x8 k1 = *(const bf16x8*)&Ks[BUF][KSWZ(32 + l31, ch)];                     \
            bf16x8 k2 = *(const bf16x8*)&Ks[BUF][KSWZ(64 + l31, ch)];                     \
            bf16x8 k3 = *(const bf16x8*)&Ks[BUF][KSWZ(96 + l31, ch)];                     \
            sA0 = __builtin_amdgcn_mfma_f32_32x32x16_bf16(k0, qf[ks], sA0, 0, 0, 0);      \
            sA1 = __builtin_amdgcn_mfma_f32_32x32x16_bf16(k1, qf[ks], sA1, 0, 0, 0);      \
            sB0 = __builtin_amdgcn_mfma_f32_32x32x16_bf16(k2, qf[ks], sB0, 0, 0, 0);      \
            sB1 = __builtin_amdgcn_mfma_f32_32x32x16_bf16(k3, qf[ks], sB1, 0, 0, 0);      \
        }                                                                                 \
        {                                                                                 \
            U4 ab; ab.u[1] = 0; ab.u[2] = 0; ab.u[3] = 0;                                 \
            unsigned bvx;                                                                 \
            bvx = ((mr0 >> l31) & 1u) ? 0xC943u : 0u; ab.u[0] = hi ? 0u : bvx;            \
            sA0 = __builtin_amdgcn_mfma_f32_32x32x16_bf16(ab.v, ones.v, sA0, 0, 0, 0);    \
            bvx = ((mr1 >> l31) & 1u) ? 0xC943u : 0u; ab.u[0] = hi ? 0u : bvx;            \
            sA1 = __builtin_amdgcn_mfma_f32_32x32x16_bf16(ab.v, ones.v, sA1, 0, 0, 0);    \
            bvx = ((mr2 >> l31) & 1u) ? 0xC943u : 0u; ab.u[0] = hi ? 0u : bvx;            \
            sB0 = __builtin_amdgcn_mfma_f32_32x32x16_bf16(ab.v, ones.v, sB0, 0, 0, 0);    \
            bvx = ((mr3 >> l31) & 1u) ? 0xC943u : 0u; ab.u[0] = hi ? 0u : bvx;            \
            sB1 = __builtin_amdgcn_mfma_f32_32x32x16_bf16(ab.v, ones.v, sB1, 0, 0, 0);    \
        }                                                                                 \
        __builtin_amdgcn_s_setprio(0);                                                    \
        float tm[16];                                                                     \
        _Pragma("unroll")                                                                 \
        for (int r2 = 0; r2 < 16; ++r2)                                                   \
            tm[r2] = fmaxf(fmaxf(sA0[r2], sA1[r2]), fmaxf(sB0[r2], sB1[r2]));             \
        _Pragma("unroll")                                                                 \
        for (int st = 8; st; st >>= 1)                                                    \
            _Pragma("unroll")                                                             \
            for (int r2 = 0; r2 < st; ++r2)                                               \
                tm[r2] = fmaxf(tm[r2], tm[r2 + st]);                                      \
        float m = tm[0];                                                                  \
        m = fmaxf(m, xhalf(m, hi));                                                       \
        float mt = m * C2;                                                                \
        if (!__all(mt <= mrun + 11.5f)) {                                                 \
            float newm = fmaxf(mrun, mt);                                                 \
            float corr = exp2f(mrun - newm);                                              \
            _Pragma("unroll")                                                             \
            for (int r2 = 0; r2 < 16; ++r2) {                                             \
                oacc0[r2] *= corr; oacc1[r2] *= corr; sacc[r2] *= corr;                   \
            }                                                                             \
            mrun = newm;                                                                  \
        }                                                                                 \
        _Pragma("unroll")                                                                 \
        for (int r2 = 0; r2 < 16; ++r2) {                                                 \
            sA0[r2] = exp2f(fmaf(sA0[r2], C2, -mrun));                                    \
            sA1[r2] = exp2f(fmaf(sA1[r2], C2, -mrun));                                    \
            sB0[r2] = exp2f(fmaf(sB0[r2], C2, -mrun));                                    \
            sB1[r2] = exp2f(fmaf(sB1[r2], C2, -mrun));                                    \
        }                                                                                 \
        unsigned cA0[8], cA1[8], cB0[8], cB1[8];                                          \
        _Pragma("unroll")                                                                 \
        for (int ii = 0; ii < 8; ++ii) {                                                  \
            asm volatile("v_cvt_pk_bf16_f32 %0, %1, %2" : "=v"(cA0[ii]) : "v"(sA0[2 * ii]), "v"(sA0[2 * ii + 1])); \
            asm volatile("v_cvt_pk_bf16_f32 %0, %1, %2" : "=v"(cA1[ii]) : "v"(sA1[2 * ii]), "v"(sA1[2 * ii + 1])); \
            asm volatile("v_cvt_pk_bf16_f32 %0, %1, %2" : "=v"(cB0[ii]) : "v"(sB0[2 * ii]), "v"(sB0[2 * ii + 1])); \
            asm volatile("v_cvt_pk_bf16_f32 %0, %1, %2" : "=v"(cB1[ii]) : "v"(sB1[2 * ii]), "v"(sB1[2 * ii + 1])); \
        }                                                                                 \
        _Pragma("unroll")                                                                 \
        for (int g = 0; g < 8; g += 4) {                                                  \
            asm volatile("v_permlane32_swap_b32 %0, %1" : "+v"(cA0[g + 0]), "+v"(cA0[g + 2])); \
            asm volatile("v_permlane32_swap_b32 %0, %1" : "+v"(cA0[g + 1]), "+v"(cA0[g + 3])); \
            asm volatile("v_permlane32_swap_b32 %0, %1" : "+v"(cA1[g + 0]), "+v"(cA1[g + 2])); \
            asm volatile("v_permlane32_swap_b32 %0, %1" : "+v"(cA1[g + 1]), "+v"(cA1[g + 3])); \
            asm volatile("v_permlane32_swap_b32 %0, %1" : "+v"(cB0[g + 0]), "+v"(cB0[g + 2])); \
            asm volatile("v_permlane32_swap_b32 %0, %1" : "+v"(cB0[g + 1]), "+v"(cB0[g + 3])); \
            asm volatile("v_permlane32_swap_b32 %0, %1" : "+v"(cB1[g + 0]), "+v"(cB1[g + 2])); \
            asm volatile("v_permlane32_swap_b32 %0, %1" : "+v"(cB1[g + 1]), "+v"(cB1[g + 3])); \
        }                                                                                 \
        __builtin_amdgcn_s_setprio(1);                                                    \
        _Pragma("unroll")                                                                 \
        for (int t = 0; t < 8; ++t) {                                                     \
            const unsigned* cp = (t < 2) ? cA0 : (t < 4) ? cA1 : (t < 6) ? cB0 : cB1;     \
            const int g = (t & 1) * 4;                                                    \
            U4 pb;                                                                        \
            pb.u[0] = cp[g + 0]; pb.u[1] = cp[g + 1]; pb.u[2] = cp[g + 2]; pb.u[3] = cp[g + 3]; \
            const int ch = t * 16 + hi * 8;                                               \
            bf16x8 vf0 = *(const bf16x8*)&Vts[BUF][VSWZ(l31, ch)];                        \
            bf16x8 vf1 = *(const bf16x8*)&Vts[BUF][VSWZ(32 + l31, ch)];                   \
            oacc0 = __builtin_amdgcn_mfma_f32_32x32x16_bf16(vf0, pb.v, oacc0, 0, 0, 0);   \
            oacc1 = __builtin_amdgcn_mfma_f32_32x32x16_bf16(vf1, pb.v, oacc1, 0, 0, 0);   \
            sacc  = __builtin_amdgcn_mfma_f32_32x32x16_bf16(ones.v, pb.v, sacc, 0, 0, 0); \
        }                                                                                 \
        __builtin_amdgcn_s_setprio(0);                                                    \
        __syncthreads();                                                                  \
    }

    STAGE(0, 0);
    __syncthreads();
    for (int kt2 = 0; kt2 < 4; ++kt2) {
        ATILE(0, 2 * kt2, 1);
        ATILE(1, 2 * kt2 + 1, (kt2 < 3));
    }
#undef ATILE
#undef STAGE
#undef KSWZ
#undef VSWZ
    const float rl = 1.f / sacc[0];
    const int b2 = bh & 3, h2 = bh >> 2;   // faithful-to-torch head scramble
    const size_t rowbase = ((size_t)b2 * SEQ + q0 + l31) * D_MODEL + h2 * 64 + 4 * hi;
    #pragma unroll
    for (int df = 0; df < 2; ++df) {
        const f32x16& oa = df ? oacc1 : oacc0;
        #pragma unroll
        for (int rg = 0; rg < 4; ++rg) {
            ushort4 pk;
            pk.x = f2bf(oa[rg * 4 + 0] * rl);
            pk.y = f2bf(oa[rg * 4 + 1] * rl);
            pk.z = f2bf(oa[rg * 4 + 2] * rl);
            pk.w = f2bf(oa[rg * 4 + 3] * rl);
            *(ushort4*)&AF[rowbase + 32 * df + 8 * rg] = pk;
        }
    }
}

// ---------------- residual + LayerNorm (bf16 attn_out + f32 residual) ----------------
__global__ __launch_bounds__(256) void ln_kernel(const unsigned short* __restrict__ tmpb,
                                                 const float* __restrict__ inp,
                                                 const float* __restrict__ g,
                                                 const float* __restrict__ bb,
                                                 float* __restrict__ out) {
    __shared__ float red[8];
    const int row = blockIdx.x, tid = threadIdx.x;
    ushort4 t4 = ((const ushort4*)(tmpb + (size_t)row * D_MODEL))[tid];
    float4 rr = ((const float4*)(inp + (size_t)row * D_MODEL))[tid];
    float4 y;
    y.x = bf2f(t4.x) + rr.x; y.y = bf2f(t4.y) + rr.y;
    y.z = bf2f(t4.z) + rr.z; y.w = bf2f(t4.w) + rr.w;
    float sum = y.x + y.y + y.z + y.w;
    float sq = y.x * y.x + y.y * y.y + y.z * y.z + y.w * y.w;
    #pragma unroll
    for (int o = 1; o < 64; o <<= 1) { sum += __shfl_xor(sum, o); sq += __shfl_xor(sq, o); }
    int wid = tid >> 6, lane = tid & 63;
    if (lane == 0) { red[wid] = sum; red[4 + wid] = sq; }
    __syncthreads();
    sum = red[0] + red[1] + red[2] + red[3];
    sq = red[4] + red[5] + red[6] + red[7];
    float mu = sum * (1.f / D_MODEL);
    float var = sq * (1.f / D_MODEL) - mu * mu;
    float rs = rsqrtf(var + 1e-5f);
    float4 gg = ((const float4*)g)[tid];
    float4 bv = ((const float4*)bb)[tid];
    float4 o4;
    o4.x = (y.x - mu) * rs * gg.x + bv.x;
    o4.y = (y.y - mu) * rs * gg.y + bv.y;
    o4.z = (y.z - mu) * rs * gg.z + bv.z;
    o4.w = (y.w - mu) * rs * gg.w + bv.w;
    ((float4*)(out + (size_t)row * D_MODEL))[tid] = o4;
}

extern "C" void kernel_launch(void* const* d_in, const int* in_sizes, int n_in,
                              void* d_out, int out_size, void* d_ws, size_t ws_size,
                              hipStream_t stream) {
    const float* inp = (const float*)d_in[0];
    const int* amask = (const int*)d_in[1];
    const float* Wq = (const float*)d_in[2];
    const float* bq = (const float*)d_in[3];
    const float* Wk = (const float*)d_in[4];
    const float* bk = (const float*)d_in[5];
    const float* Wv = (const float*)d_in[6];
    const float* bv = (const float*)d_in[7];
    const float* Wo = (const float*)d_in[8];
    const float* lg = (const float*)d_in[9];
    const float* lb = (const float*)d_in[10];
    float* out = (float*)d_out;
    char* ws = (char*)d_ws;

    unsigned short* Xb     = (unsigned short*)(ws + 0);          //  8.0 MiB
    unsigned short* Wqkv_t = (unsigned short*)(ws + 8388608);    //  6.0 MiB
    unsigned short* Wo_t   = (unsigned short*)(ws + 14680064);   //  2.0 MiB
    unsigned short* Qb     = (unsigned short*)(ws + 16777216);   //  8.0 MiB
    unsigned short* Kb     = (unsigned short*)(ws + 25165824);   //  8.0 MiB
    unsigned short* Vt     = (unsigned short*)(ws + 33554432);   //  8.0 MiB  (V^T: [bh][d][s])
    unsigned short* AF     = (unsigned short*)(ws + 41943040);   //  8.0 MiB
    unsigned short* tmpb   = (unsigned short*)(ws + 50331648);   //  8.0 MiB  (bf16 attn_out @ Wo)
    unsigned long long* mwords = (unsigned long long*)(ws + 58720256);  // 512 B

    prep<<<8208, 256, 0, stream>>>(inp, Xb, amask, mwords, Wq, Wk, Wv, Wo, Wqkv_t, Wo_t);
    gemm_qkv<<<768, 256, 0, stream>>>(Xb, Wqkv_t, bq, bk, bv, Qb, Kb, Vt);
    attn_kernel<<<256, 512, 0, stream>>>(Qb, Kb, Vt, mwords, AF);
    gemm_o<<<256, 256, 0, stream>>>(AF, Wo_t, tmpb);
    ln_kernel<<<4096, 256, 0, stream>>>(tmpb, inp, lg, lb, out);
}

// Round 14
// 97.014 us; speedup vs baseline: 1.0267x; 1.0267x over previous
//
#include <hip/hip_runtime.h>

typedef __attribute__((ext_vector_type(8))) short bf16x8;
typedef __attribute__((ext_vector_type(4))) float f32x4;
typedef __attribute__((ext_vector_type(16))) float f32x16;

#define D_MODEL 1024
#define SEQ 1024
#define NB 4
#define NH 16
#define DH 64
#define MROWS 4096

__device__ __forceinline__ unsigned short f2bf(float f) {
    union { float f; unsigned u; } x; x.f = f;
    unsigned r = x.u + 0x7fffu + ((x.u >> 16) & 1u);
    return (unsigned short)(r >> 16);
}

__device__ __forceinline__ float bf2f(unsigned short u) {
    union { unsigned u; float f; } x; x.u = (unsigned)u << 16;
    return x.f;
}

__device__ __forceinline__ void gload16(const void* g, void* l) {
    __builtin_amdgcn_global_load_lds((const __attribute__((address_space(1))) void*)g,
                                     (__attribute__((address_space(3))) void*)l, 16, 0, 0);
}

// exchange value with lane^32 via permlane32_swap (VALU-only, no LDS)
__device__ __forceinline__ float xhalf(float x, int hi) {
    float a = x, b = x;
    asm volatile("v_permlane32_swap_b32 %0, %1" : "+v"(a), "+v"(b));
    return hi ? b : a;
}

// ---------------- fused preprocessing: cvt_x | transpose_w | pack_mask ----------------
__global__ __launch_bounds__(256) void prep(const float* __restrict__ x,
                                            unsigned short* __restrict__ Xb,
                                            const int* __restrict__ amask,
                                            unsigned long long* __restrict__ mwords,
                                            const float* __restrict__ Wq,
                                            const float* __restrict__ Wk,
                                            const float* __restrict__ Wv,
                                            const float* __restrict__ Wo,
                                            unsigned short* __restrict__ Wqkv_t,
                                            unsigned short* __restrict__ Wo_t) {
    __shared__ float tile[32][33];
    const int bid = blockIdx.x, tid = threadIdx.x;
    if (bid < 4096) {
        int i = bid * 256 + tid;
        float4 v = ((const float4*)x)[i];
        ushort4 r;
        r.x = f2bf(v.x); r.y = f2bf(v.y); r.z = f2bf(v.z); r.w = f2bf(v.w);
        ((ushort4*)Xb)[i] = r;
    } else if (bid < 8192) {
        int t = bid - 4096;
        const int mtx = t >> 10, t10 = t & 1023;
        const float* src = mtx == 0 ? Wq : mtx == 1 ? Wk : mtx == 2 ? Wv : Wo;
        unsigned short* dst = mtx < 3 ? (Wqkv_t + (size_t)mtx * D_MODEL * D_MODEL) : Wo_t;
        const int n0 = (t10 & 31) * 32, k0 = (t10 >> 5) * 32;
        const int tx = tid & 31, ty = tid >> 5;   // 32 x 8
        #pragma unroll
        for (int i = 0; i < 32; i += 8)
            tile[ty + i][tx] = src[(size_t)(k0 + ty + i) * D_MODEL + n0 + tx];
        __syncthreads();
        #pragma unroll
        for (int i = 0; i < 32; i += 8)
            dst[(size_t)(n0 + ty + i) * D_MODEL + k0 + tx] = f2bf(tile[tx][ty + i]);
    } else {
        int word = (bid - 8192) * 4 + (tid >> 6);
        int lane = tid & 63;
        unsigned long long m = __ballot(amask[word * 64 + lane] != 0);
        if (lane == 0) mwords[word] = m;
    }
}

// Cs swizzled addressing: stride 128 shorts, XOR bits 3..5 of col with row&7
#define CSW(r, c) ((r) * 128 + ((c) ^ (((r) & 7) << 3)))

// ---------------- QKV GEMM: BK=64, double-buffered, unrolled x2 (buf compile-time) ----------------
__global__ __launch_bounds__(256) void gemm_qkv(const unsigned short* __restrict__ Xb,
                                                const unsigned short* __restrict__ Wt,
                                                const float* __restrict__ bq,
                                                const float* __restrict__ bk,
                                                const float* __restrict__ bv,
                                                unsigned short* __restrict__ Qb,
                                                unsigned short* __restrict__ Kb,
                                                unsigned short* __restrict__ Vt) {
    __shared__ unsigned short SM[32768];   // 64 KB: [buf][A 8192 | B 8192]; Cs aliases first 32 KB
    const int tid = threadIdx.x;
    const int lane = tid & 63, wid = tid >> 6;
    const int fr = lane & 15, fg = lane >> 4;
    const int wr = wid >> 1, wc = wid & 1;
    const int lin = blockIdx.x;
    const int x = lin & 7, i = lin >> 3;
    const int bxm = (x & 3) * 8 + (i & 7);
    const int byn = (x >> 2) * 12 + (i >> 3);
    const int m0 = bxm * 128, n0 = byn * 128;
    const unsigned short* Ag = Xb + (size_t)m0 * D_MODEL;
    const unsigned short* Bg = Wt + (size_t)n0 * D_MODEL;
    const int srow = tid >> 3;
    const int scol = 8 * ((tid & 7) ^ ((tid >> 3) & 7));
    f32x4 acc[4][4] = {};

#define QSTAGE(bf, kt2)                                                                   \
    {                                                                                     \
        const int kb = (kt2) * 64;                                                        \
        _Pragma("unroll")                                                                 \
        for (int j = 0; j < 4; ++j) {                                                     \
            int row = j * 32 + srow;                                                      \
            gload16(Ag + (size_t)row * D_MODEL + kb + scol, &SM[(bf) * 16384 + (j * 256 + tid) * 8]); \
            gload16(Bg + (size_t)row * D_MODEL + kb + scol, &SM[(bf) * 16384 + 8192 + (j * 256 + tid) * 8]); \
        }                                                                                 \
    }

#define QSTEP(BUF, KT, DOPF)                                                              \
    {                                                                                     \
        if (DOPF) QSTAGE((BUF) ^ 1, (KT) + 1);                                            \
        const unsigned short* As = &SM[(BUF) * 16384];                                    \
        const unsigned short* Bs = &SM[(BUF) * 16384 + 8192];                             \
        _Pragma("unroll")                                                                 \
        for (int ks = 0; ks < 2; ++ks) {                                                  \
            bf16x8 af[4], bfv[4];                                                         \
            _Pragma("unroll")                                                             \
            for (int m = 0; m < 4; ++m) {                                                 \
                int row = wr * 64 + m * 16 + fr;                                          \
                af[m] = *(const bf16x8*)&As[row * 64 + ((ks * 32 + fg * 8) ^ ((row & 7) * 8))]; \
            }                                                                             \
            _Pragma("unroll")                                                             \
            for (int n = 0; n < 4; ++n) {                                                 \
                int row = wc * 64 + n * 16 + fr;                                          \
                bfv[n] = *(const bf16x8*)&Bs[row * 64 + ((ks * 32 + fg * 8) ^ ((row & 7) * 8))]; \
            }                                                                             \
            __builtin_amdgcn_s_setprio(1);                                                \
            _Pragma("unroll")                                                             \
            for (int m = 0; m < 4; ++m)                                                   \
                _Pragma("unroll")                                                         \
                for (int n = 0; n < 4; ++n)                                               \
                    acc[m][n] = __builtin_amdgcn_mfma_f32_16x16x32_bf16(af[m], bfv[n], acc[m][n], 0, 0, 0); \
            __builtin_amdgcn_s_setprio(0);                                                \
        }                                                                                 \
        __syncthreads();                                                                  \
    }

    QSTAGE(0, 0);
    __syncthreads();
    for (int kt2 = 0; kt2 < 8; ++kt2) {
        QSTEP(0, 2 * kt2, 1);
        QSTEP(1, 2 * kt2 + 1, (kt2 < 7));
    }
#undef QSTEP
#undef QSTAGE
    unsigned short* Cs = SM;
    const int sel = n0 >> 10;
    const int npb = n0 & 1023;
    if (sel < 2) {
        #pragma unroll
        for (int n = 0; n < 4; ++n) {
            int cn = wc * 64 + n * 16 + fr;
            float bias = (sel == 0 ? bq : bk)[npb + cn];
            #pragma unroll
            for (int m = 0; m < 4; ++m)
                #pragma unroll
                for (int r = 0; r < 4; ++r) {
                    int row = wr * 64 + m * 16 + fg * 4 + r;
                    Cs[CSW(row, cn)] = f2bf(acc[m][n][r] + bias);
                }
        }
        __syncthreads();
        unsigned short* dst = sel == 0 ? Qb : Kb;
        #pragma unroll
        for (int k = 0; k < 8; ++k) {
            int c = k * 256 + tid;
            int row = c >> 4, cc = c & 15;
            int np = npb + cc * 8;
            int h = np >> 6, d = np & 63;
            int gm = m0 + row, b = gm >> 10, s = gm & 1023;
            bf16x8 v = *(const bf16x8*)&Cs[CSW(row, cc * 8)];
            *(bf16x8*)&dst[((size_t)(b * NH + h) * SEQ + s) * DH + d] = v;
        }
    } else {
        #pragma unroll
        for (int n = 0; n < 4; ++n) {
            int cn = wc * 64 + n * 16 + fr;
            float bias = bv[npb + cn];
            #pragma unroll
            for (int m = 0; m < 4; ++m)
                #pragma unroll
                for (int r = 0; r < 4; ++r) {
                    int row = wr * 64 + m * 16 + fg * 4 + r;   // s index
                    Cs[CSW(cn, row)] = f2bf(acc[m][n][r] + bias);
                }
        }
        __syncthreads();
        #pragma unroll
        for (int k = 0; k < 8; ++k) {
            int c = k * 256 + tid;
            int dcol = c >> 4, scc = c & 15;
            int np = npb + dcol;
            int h = np >> 6, dd = np & 63;
            int gm0 = m0 + scc * 8, b = gm0 >> 10, s0 = gm0 & 1023;
            bf16x8 v = *(const bf16x8*)&Cs[CSW(dcol, scc * 8)];
            *(bf16x8*)&Vt[((size_t)(b * NH + h) * DH + dd) * SEQ + s0] = v;
        }
    }
}

// ---------------- O-proj GEMM: BK=64, double-buffered, unrolled x2, bf16 output ----------------
__global__ __launch_bounds__(256) void gemm_o(const unsigned short* __restrict__ Ab,
                                              const unsigned short* __restrict__ Wt,
                                              unsigned short* __restrict__ tmpb) {
    __shared__ unsigned short SM[32768];   // 64 KB dbuf; Cs aliases first 32 KB
    const int tid = threadIdx.x;
    const int lane = tid & 63, wid = tid >> 6;
    const int fr = lane & 15, fg = lane >> 4;
    const int wr = wid >> 1, wc = wid & 1;
    const int lin = blockIdx.x;
    const int x = lin & 7, i = lin >> 3;
    const int bxm = (x & 3) * 8 + (i & 7);
    const int byn = (x >> 2) * 4 + (i >> 3);
    const int m0 = bxm * 128, n0 = byn * 128;
    const unsigned short* Ag = Ab + (size_t)m0 * D_MODEL;
    const unsigned short* Bg = Wt + (size_t)n0 * D_MODEL;
    const int srow = tid >> 3;
    const int scol = 8 * ((tid & 7) ^ ((tid >> 3) & 7));
    f32x4 acc[4][4] = {};

#define OSTAGE(bf, kt2)                                                                   \
    {                                                                                     \
        const int kb = (kt2) * 64;                                                        \
        _Pragma("unroll")                                                                 \
        for (int j = 0; j < 4; ++j) {                                                     \
            int row = j * 32 + srow;                                                      \
            gload16(Ag + (size_t)row * D_MODEL + kb + scol, &SM[(bf) * 16384 + (j * 256 + tid) * 8]); \
            gload16(Bg + (size_t)row * D_MODEL + kb + scol, &SM[(bf) * 16384 + 8192 + (j * 256 + tid) * 8]); \
        }                                                                                 \
    }

#define OSTEP(BUF, KT, DOPF)                                                              \
    {                                                                                     \
        if (DOPF) OSTAGE((BUF) ^ 1, (KT) + 1);                                            \
        const unsigned short* As = &SM[(BUF) * 16384];                                    \
        const unsigned short* Bs = &SM[(BUF) * 16384 + 8192];                             \
        _Pragma("unroll")                                                                 \
        for (int ks = 0; ks < 2; ++ks) {                                                  \
            bf16x8 af[4], bfv[4];                                                         \
            _Pragma("unroll")                                                             \
            for (int m = 0; m < 4; ++m) {                                                 \
                int row = wr * 64 + m * 16 + fr;                                          \
                af[m] = *(const bf16x8*)&As[row * 64 + ((ks * 32 + fg * 8) ^ ((row & 7) * 8))]; \
            }                                                                             \
            _Pragma("unroll")                                                             \
            for (int n = 0; n < 4; ++n) {                                                 \
                int row = wc * 64 + n * 16 + fr;                                          \
                bfv[n] = *(const bf16x8*)&Bs[row * 64 + ((ks * 32 + fg * 8) ^ ((row & 7) * 8))]; \
            }                                                                             \
            __builtin_amdgcn_s_setprio(1);                                                \
            _Pragma("unroll")                                                             \
            for (int m = 0; m < 4; ++m)                                                   \
                _Pragma("unroll")                                                         \
                for (int n = 0; n < 4; ++n)                                               \
                    acc[m][n] = __builtin_amdgcn_mfma_f32_16x16x32_bf16(af[m], bfv[n], acc[m][n], 0, 0, 0); \
            __builtin_amdgcn_s_setprio(0);                                                \
        }                                                                                 \
        __syncthreads();                                                                  \
    }

    OSTAGE(0, 0);
    __syncthreads();
    for (int kt2 = 0; kt2 < 8; ++kt2) {
        OSTEP(0, 2 * kt2, 1);
        OSTEP(1, 2 * kt2 + 1, (kt2 < 7));
    }
#undef OSTEP
#undef OSTAGE
    unsigned short* Cs = SM;
    #pragma unroll
    for (int n = 0; n < 4; ++n) {
        int cn = wc * 64 + n * 16 + fr;
        #pragma unroll
        for (int m = 0; m < 4; ++m)
            #pragma unroll
            for (int r = 0; r < 4; ++r) {
                int row = wr * 64 + m * 16 + fg * 4 + r;
                Cs[CSW(row, cn)] = f2bf(acc[m][n][r]);
            }
    }
    __syncthreads();
    #pragma unroll
    for (int k = 0; k < 8; ++k) {
        int c = k * 256 + tid;
        int row = c >> 4, cc = c & 15;
        bf16x8 v = *(const bf16x8*)&Cs[CSW(row, cc * 8)];
        *(bf16x8*)&tmpb[(size_t)(m0 + row) * D_MODEL + n0 + cc * 8] = v;
    }
}

// ---------------- flash attention: KVBLK=128, in-register softmax, unrolled x2 (R12 config) ----------------
// Mask applied as K-side bias MFMA; row-sum on the matrix pipe via mfma(ones, P).
__global__ __launch_bounds__(256, 2) void attn_kernel(const unsigned short* __restrict__ Qb,
                                                      const unsigned short* __restrict__ Kb,
                                                      const unsigned short* __restrict__ Vt,
                                                      const unsigned long long* __restrict__ mwords,
                                                      unsigned short* __restrict__ AF) {
    __shared__ unsigned short Ks[2][128 * 64];   // [kv][d]
    __shared__ unsigned short Vts[2][64 * 128];  // [d][kv]
    const int tid = threadIdx.x, lane = tid & 63, wid = tid >> 6;
    const int l31 = lane & 31, hi = lane >> 5;
    const int lin = blockIdx.x;
    const int x = lin & 7, i = lin >> 3;
    const int qt = i & 7, bh = x * 8 + (i >> 3);
    const int b = bh >> 4;
    const unsigned short* Qh = Qb + (size_t)bh * SEQ * DH;
    const unsigned short* Kh = Kb + (size_t)bh * SEQ * DH;
    const unsigned short* Vth = Vt + (size_t)bh * DH * SEQ;
    const unsigned long long* mwb = mwords + b * 16;
    const int q0 = qt * 128 + wid * 32;

    const int k_row = wid * 32 + (lane >> 3);
    const int k_col = 8 * ((lane & 7) ^ ((lane >> 3) & 7));
    const int v_rowb = wid * 16 + (lane >> 4);

    bf16x8 qf[4];
    #pragma unroll
    for (int ks = 0; ks < 4; ++ks)
        qf[ks] = *(const bf16x8*)(Qh + (size_t)(q0 + l31) * DH + ks * 16 + hi * 8);

    union U4 { unsigned u[4]; bf16x8 v; };
    U4 ones;
    ones.u[0] = 0x3F803F80u; ones.u[1] = 0x3F803F80u;
    ones.u[2] = 0x3F803F80u; ones.u[3] = 0x3F803F80u;

    f32x16 oacc0 = {}, oacc1 = {};
    f32x16 sacc = {};                // running P row-sum (all 16 regs identical)
    float mrun = -3.0e38f;
    const float C2 = 0.18033688f;    // 0.125 * log2(e)

#define KSWZ(row, colsh) ((row) * 64 + ((colsh) ^ (((row) & 7) << 3)))
#define VSWZ(row, colsh) ((row) * 128 + ((colsh) ^ (((row) & 7) << 3)))
#define STAGE(bufi, kt2)                                                                  \
    {                                                                                     \
        const int kv0s = (kt2) * 128;                                                     \
        _Pragma("unroll")                                                                 \
        for (int j = 0; j < 4; ++j)                                                       \
            gload16(Kh + (size_t)(kv0s + k_row + j * 8) * DH + k_col,                     \
                    &Ks[bufi][wid * 2048 + j * 512]);                                     \
        _Pragma("unroll")                                                                 \
        for (int j = 0; j < 4; ++j) {                                                     \
            const int vr = v_rowb + j * 4;                                                \
            gload16(Vth + (size_t)vr * SEQ + kv0s + 8 * ((lane & 15) ^ (vr & 7)),         \
                    &Vts[bufi][wid * 2048 + j * 512]);                                    \
        }                                                                                 \
    }

#define ATILE(BUF, KT, DOPF, DOBAR)                                                       \
    {                                                                                     \
        if (DOPF) STAGE((BUF) ^ 1, (KT) + 1);                                             \
        const unsigned long long mwA = mwb[2 * (KT)], mwB = mwb[2 * (KT) + 1];            \
        const unsigned mr0 = (unsigned)mwA, mr1 = (unsigned)(mwA >> 32);                  \
        const unsigned mr2 = (unsigned)mwB, mr3 = (unsigned)(mwB >> 32);                  \
        f32x16 sA0 = {}, sA1 = {}, sB0 = {}, sB1 = {};                                    \
        __builtin_amdgcn_s_setprio(1);                                                    \
        _Pragma("unroll")                                                                 \
        for (int ks = 0; ks < 4; ++ks) {                                                  \
            const int ch = ks * 16 + hi * 8;                                              \
            bf16x8 k0 = *(const bf16x8*)&Ks[BUF][KSWZ(l31, ch)];                          \
            bf16x8 k1 = *(const bf16x8*)&Ks[BUF][KSWZ(32 + l31, ch)];                     \
            bf16x8 k2 = *(const bf16x8*)&Ks[BUF][KSWZ(64 + l31, ch)];                     \
            bf16x8 k3 = *(const bf16x8*)&Ks[BUF][KSWZ(96 + l31, ch)];                     \
            sA0 = __builtin_amdgcn_mfma_f32_32x32x16_bf16(k0, qf[ks], sA0, 0, 0, 0);      \
            sA1 = __builtin_amdgcn_mfma_f32_32x32x16_bf16(k1, qf[ks], sA1, 0, 0, 0);      \
            sB0 = __builtin_amdgcn_mfma_f32_32x32x16_bf16(k2, qf[ks], sB0, 0, 0, 0);      \
            sB1 = __builtin_amdgcn_mfma_f32_32x32x16_bf16(k3, qf[ks], sB1, 0, 0, 0);      \
        }                                                                                 \
        {                                                                                 \
            U4 ab; ab.u[1] = 0; ab.u[2] = 0; ab.u[3] = 0;                                 \
            unsigned bvx;                                                                 \
            bvx = ((mr0 >> l31) & 1u) ? 0xC943u : 0u; ab.u[0] = hi ? 0u : bvx;            \
            sA0 = __builtin_amdgcn_mfma_f32_32x32x16_bf16(ab.v, ones.v, sA0, 0, 0, 0);    \
            bvx = ((mr1 >> l31) & 1u) ? 0xC943u : 0u; ab.u[0] = hi ? 0u : bvx;            \
            sA1 = __builtin_amdgcn_mfma_f32_32x32x16_bf16(ab.v, ones.v, sA1, 0, 0, 0);    \
            bvx = ((mr2 >> l31) & 1u) ? 0xC943u : 0u; ab.u[0] = hi ? 0u : bvx;            \
            sB0 = __builtin_amdgcn_mfma_f32_32x32x16_bf16(ab.v, ones.v, sB0, 0, 0, 0);    \
            bvx = ((mr3 >> l31) & 1u) ? 0xC943u : 0u; ab.u[0] = hi ? 0u : bvx;            \
            sB1 = __builtin_amdgcn_mfma_f32_32x32x16_bf16(ab.v, ones.v, sB1, 0, 0, 0);    \
        }                                                                                 \
        __builtin_amdgcn_s_setprio(0);                                                    \
        float tm[16];                                                                     \
        _Pragma("unroll")                                                                 \
        for (int r2 = 0; r2 < 16; ++r2)                                                   \
            tm[r2] = fmaxf(fmaxf(sA0[r2], sA1[r2]), fmaxf(sB0[r2], sB1[r2]));             \
        _Pragma("unroll")                                                                 \
        for (int st = 8; st; st >>= 1)                                                    \
            _Pragma("unroll")                                                             \
            for (int r2 = 0; r2 < st; ++r2)                                               \
                tm[r2] = fmaxf(tm[r2], tm[r2 + st]);                                      \
        float m = tm[0];                                                                  \
        m = fmaxf(m, xhalf(m, hi));                                                       \
        float mt = m * C2;                                                                \
        if (!__all(mt <= mrun + 11.5f)) {                                                 \
            float newm = fmaxf(mrun, mt);                                                 \
            float corr = exp2f(mrun - newm);                                              \
            _Pragma("unroll")                                                             \
            for (int r2 = 0; r2 < 16; ++r2) {                                             \
                oacc0[r2] *= corr; oacc1[r2] *= corr; sacc[r2] *= corr;                   \
            }                                                                             \
            mrun = newm;                                                                  \
        }                                                                                 \
        _Pragma("unroll")                                                                 \
        for (int r2 = 0; r2 < 16; ++r2) {                                                 \
            sA0[r2] = exp2f(fmaf(sA0[r2], C2, -mrun));                                    \
            sA1[r2] = exp2f(fmaf(sA1[r2], C2, -mrun));                                    \
            sB0[r2] = exp2f(fmaf(sB0[r2], C2, -mrun));                                    \
            sB1[r2] = exp2f(fmaf(sB1[r2], C2, -mrun));                                    \
        }                                                                                 \
        unsigned cA0[8], cA1[8], cB0[8], cB1[8];                                          \
        _Pragma("unroll")                                                                 \
        for (int ii = 0; ii < 8; ++ii) {                                                  \
            asm volatile("v_cvt_pk_bf16_f32 %0, %1, %2" : "=v"(cA0[ii]) : "v"(sA0[2 * ii]), "v"(sA0[2 * ii + 1])); \
            asm volatile("v_cvt_pk_bf16_f32 %0, %1, %2" : "=v"(cA1[ii]) : "v"(sA1[2 * ii]), "v"(sA1[2 * ii + 1])); \
            asm volatile("v_cvt_pk_bf16_f32 %0, %1, %2" : "=v"(cB0[ii]) : "v"(sB0[2 * ii]), "v"(sB0[2 * ii + 1])); \
            asm volatile("v_cvt_pk_bf16_f32 %0, %1, %2" : "=v"(cB1[ii]) : "v"(sB1[2 * ii]), "v"(sB1[2 * ii + 1])); \
        }                                                                                 \
        _Pragma("unroll")                                                                 \
        for (int g = 0; g < 8; g += 4) {                                                  \
            asm volatile("v_permlane32_swap_b32 %0, %1" : "+v"(cA0[g + 0]), "+v"(cA0[g + 2])); \
            asm volatile("v_permlane32_swap_b32 %0, %1" : "+v"(cA0[g + 1]), "+v"(cA0[g + 3])); \
            asm volatile("v_permlane32_swap_b32 %0, %1" : "+v"(cA1[g + 0]), "+v"(cA1[g + 2])); \
            asm volatile("v_permlane32_swap_b32 %0, %1" : "+v"(cA1[g + 1]), "+v"(cA1[g + 3])); \
            asm volatile("v_permlane32_swap_b32 %0, %1" : "+v"(cB0[g + 0]), "+v"(cB0[g + 2])); \
            asm volatile("v_permlane32_swap_b32 %0, %1" : "+v"(cB0[g + 1]), "+v"(cB0[g + 3])); \
            asm volatile("v_permlane32_swap_b32 %0, %1" : "+v"(cB1[g + 0]), "+v"(cB1[g + 2])); \
            asm volatile("v_permlane32_swap_b32 %0, %1" : "+v"(cB1[g + 1]), "+v"(cB1[g + 3])); \
        }                                                                                 \
        __builtin_amdgcn_s_setprio(1);                                                    \
        _Pragma("unroll")                                                                 \
        for (int t = 0; t < 8; ++t) {                                                     \
            const unsigned* cp = (t < 2) ? cA0 : (t < 4) ? cA1 : (t < 6) ? cB0 : cB1;     \
            const int g = (t & 1) * 4;                                                    \
            U4 pb;                                                                        \
            pb.u[0] = cp[g + 0]; pb.u[1] = cp[g + 1]; pb.u[2] = cp[g + 2]; pb.u[3] = cp[g + 3]; \
            const int ch = t * 16 + hi * 8;                                               \
            bf16x8 vf0 = *(const bf16x8*)&Vts[BUF][VSWZ(l31, ch)];                        \
            bf16x8 vf1 = *(const bf16x8*)&Vts[BUF][VSWZ(32 + l31, ch)];                   \
            oacc0 = __builtin_amdgcn_mfma_f32_32x32x16_bf16(vf0, pb.v, oacc0, 0, 0, 0);   \
            oacc1 = __builtin_amdgcn_mfma_f32_32x32x16_bf16(vf1, pb.v, oacc1, 0, 0, 0);   \
            sacc  = __builtin_amdgcn_mfma_f32_32x32x16_bf16(ones.v, pb.v, sacc, 0, 0, 0); \
        }                                                                                 \
        __builtin_amdgcn_s_setprio(0);                                                    \
        if (DOBAR) __syncthreads();                                                       \
    }

    STAGE(0, 0);
    __syncthreads();
    for (int kt2 = 0; kt2 < 4; ++kt2) {
        ATILE(0, 2 * kt2, 1, 1);
        ATILE(1, 2 * kt2 + 1, (kt2 < 3), (kt2 < 3));
    }
#undef ATILE
#undef STAGE
#undef KSWZ
#undef VSWZ
    const float rl = 1.f / sacc[0];
    const int b2 = bh & 3, h2 = bh >> 2;   // faithful-to-torch head scramble
    const size_t rowbase = ((size_t)b2 * SEQ + q0 + l31) * D_MODEL + h2 * 64 + 4 * hi;
    #pragma unroll
    for (int df = 0; df < 2; ++df) {
        const f32x16& oa = df ? oacc1 : oacc0;
        #pragma unroll
        for (int rg = 0; rg < 4; ++rg) {
            ushort4 pk;
            pk.x = f2bf(oa[rg * 4 + 0] * rl);
            pk.y = f2bf(oa[rg * 4 + 1] * rl);
            pk.z = f2bf(oa[rg * 4 + 2] * rl);
            pk.w = f2bf(oa[rg * 4 + 3] * rl);
            *(ushort4*)&AF[rowbase + 32 * df + 8 * rg] = pk;
        }
    }
}

// ---------------- residual + LayerNorm (bf16 attn_out + f32 residual) ----------------
__global__ __launch_bounds__(256) void ln_kernel(const unsigned short* __restrict__ tmpb,
                                                 const float* __restrict__ inp,
                                                 const float* __restrict__ g,
                                                 const float* __restrict__ bb,
                                                 float* __restrict__ out) {
    __shared__ float red[8];
    const int row = blockIdx.x, tid = threadIdx.x;
    ushort4 t4 = ((const ushort4*)(tmpb + (size_t)row * D_MODEL))[tid];
    float4 rr = ((const float4*)(inp + (size_t)row * D_MODEL))[tid];
    float4 y;
    y.x = bf2f(t4.x) + rr.x; y.y = bf2f(t4.y) + rr.y;
    y.z = bf2f(t4.z) + rr.z; y.w = bf2f(t4.w) + rr.w;
    float sum = y.x + y.y + y.z + y.w;
    float sq = y.x * y.x + y.y * y.y + y.z * y.z + y.w * y.w;
    #pragma unroll
    for (int o = 1; o < 64; o <<= 1) { sum += __shfl_xor(sum, o); sq += __shfl_xor(sq, o); }
    int wid = tid >> 6, lane = tid & 63;
    if (lane == 0) { red[wid] = sum; red[4 + wid] = sq; }
    __syncthreads();
    sum = red[0] + red[1] + red[2] + red[3];
    sq = red[4] + red[5] + red[6] + red[7];
    float mu = sum * (1.f / D_MODEL);
    float var = sq * (1.f / D_MODEL) - mu * mu;
    float rs = rsqrtf(var + 1e-5f);
    float4 gg = ((const float4*)g)[tid];
    float4 bv = ((const float4*)bb)[tid];
    float4 o4;
    o4.x = (y.x - mu) * rs * gg.x + bv.x;
    o4.y = (y.y - mu) * rs * gg.y + bv.y;
    o4.z = (y.z - mu) * rs * gg.z + bv.z;
    o4.w = (y.w - mu) * rs * gg.w + bv.w;
    ((float4*)(out + (size_t)row * D_MODEL))[tid] = o4;
}

extern "C" void kernel_launch(void* const* d_in, const int* in_sizes, int n_in,
                              void* d_out, int out_size, void* d_ws, size_t ws_size,
                              hipStream_t stream) {
    const float* inp = (const float*)d_in[0];
    const int* amask = (const int*)d_in[1];
    const float* Wq = (const float*)d_in[2];
    const float* bq = (const float*)d_in[3];
    const float* Wk = (const float*)d_in[4];
    const float* bk = (const float*)d_in[5];
    const float* Wv = (const float*)d_in[6];
    const float* bv = (const float*)d_in[7];
    const float* Wo = (const float*)d_in[8];
    const float* lg = (const float*)d_in[9];
    const float* lb = (const float*)d_in[10];
    float* out = (float*)d_out;
    char* ws = (char*)d_ws;

    unsigned short* Xb     = (unsigned short*)(ws + 0);          //  8.0 MiB
    unsigned short* Wqkv_t = (unsigned short*)(ws + 8388608);    //  6.0 MiB
    unsigned short* Wo_t   = (unsigned short*)(ws + 14680064);   //  2.0 MiB
    unsigned short* Qb     = (unsigned short*)(ws + 16777216);   //  8.0 MiB
    unsigned short* Kb     = (unsigned short*)(ws + 25165824);   //  8.0 MiB
    unsigned short* Vt     = (unsigned short*)(ws + 33554432);   //  8.0 MiB  (V^T: [bh][d][s])
    unsigned short* AF     = (unsigned short*)(ws + 41943040);   //  8.0 MiB
    unsigned short* tmpb   = (unsigned short*)(ws + 50331648);   //  8.0 MiB  (bf16 attn_out @ Wo)
    unsigned long long* mwords = (unsigned long long*)(ws + 58720256);  // 512 B

    prep<<<8208, 256, 0, stream>>>(inp, Xb, amask, mwords, Wq, Wk, Wv, Wo, Wqkv_t, Wo_t);
    gemm_qkv<<<768, 256, 0, stream>>>(Xb, Wqkv_t, bq, bk, bv, Qb, Kb, Vt);
    attn_kernel<<<512, 256, 0, stream>>>(Qb, Kb, Vt, mwords, AF);
    gemm_o<<<256, 256, 0, stream>>>(AF, Wo_t, tmpb);
    ln_kernel<<<4096, 256, 0, stream>>>(tmpb, inp, lg, lb, out);
}